// Round 9
// baseline (1055.648 us; speedup 1.0000x reference)
//
#include <hip/hip_runtime.h>
#include <hip/hip_bf16.h>

// Problem dims
#define PP 512
#define QQ 64
#define BB 16
#define EE 256
#define HH 256
#define OO 256

typedef _Float16 half2_t __attribute__((ext_vector_type(2)));
typedef _Float16 f16x8 __attribute__((ext_vector_type(8)));
typedef float f32x4 __attribute__((ext_vector_type(4)));

__device__ __forceinline__ float fast_tanh(float x) {
    x = fminf(fmaxf(x, -15.f), 15.f);
    float e = __expf(2.f * x);
    return (e - 1.f) * __frcp_rn(e + 1.f);
}
__device__ __forceinline__ float fast_sigmoid(float x) {
    x = fminf(fmaxf(x, -30.f), 30.f);
    return __frcp_rn(1.f + __expf(-x));
}
__device__ __forceinline__ f16x8 cvt8(const float* __restrict__ p) {
    float4 r0 = *(const float4*)(p);
    float4 r1 = *(const float4*)(p + 4);
    f16x8 t;
    t[0] = (_Float16)r0.x; t[1] = (_Float16)r0.y;
    t[2] = (_Float16)r0.z; t[3] = (_Float16)r0.w;
    t[4] = (_Float16)r1.x; t[5] = (_Float16)r1.y;
    t[6] = (_Float16)r1.z; t[7] = (_Float16)r1.w;
    return t;
}
__device__ __forceinline__ float fdot2f(half2_t a, half2_t b, float c) {
#if defined(__has_builtin)
#if __has_builtin(__builtin_amdgcn_fdot2)
    return __builtin_amdgcn_fdot2(a, b, c, false);
#else
    return (float)a[0] * (float)b[0] + (float)a[1] * (float)b[1] + c;
#endif
#else
    return (float)a[0] * (float)b[0] + (float)a[1] * (float)b[1] + c;
#endif
}

// LDS-only barrier: orders ds_write -> barrier -> ds_read WITHOUT the
// vmcnt(0)/expcnt(0) drain __syncthreads() emits.
__device__ __forceinline__ void block_sync_lds() {
    __builtin_amdgcn_sched_barrier(0);
    asm volatile("s_waitcnt lgkmcnt(0)" ::: "memory");
    __builtin_amdgcn_s_barrier();
    __builtin_amdgcn_sched_barrier(0);
}

// ---------------------------------------------------------------------------
// MFMA GEMM with register-resident B (unchanged from round 6 -- verified).
// ---------------------------------------------------------------------------
template <int AMODE, int EPI, int BN, int KK>
__global__ __launch_bounds__(256)
__attribute__((amdgpu_waves_per_eu(2, 2)))
void gemm_mfma(
    const float* __restrict__ Af32,
    const _Float16* __restrict__ Ah,
    const float* __restrict__ Bw,
    const float* __restrict__ bias,
    const _Float16* __restrict__ gateC,
    _Float16* __restrict__ Cout, int M, int N)
{
    constexpr int NT = BN / 16;   // n-tiles per block (4 or 2)
    constexpr int KS = KK / 32;   // k-steps (8 or 16)
    const int tid = threadIdx.x;
    const int w = tid >> 6;
    const int lane = tid & 63;
    const int ln = lane & 15;     // fragment n / m index
    const int lk = lane >> 4;     // fragment k-group
    const int bm = blockIdx.x, bn = blockIdx.y;

    // ---- park B-strip in fragments (AGPR-resident across the k-loop) ----
    f16x8 bf[NT][KS];
#pragma unroll
    for (int c = 0; c < NT; c++) {
        const float* wp = Bw + (long)(bn * BN + c * 16 + ln) * KK + 8 * lk;
#pragma unroll
        for (int kk = 0; kk < KS; kk++) bf[c][kk] = cvt8(wp + kk * 32);
    }

    const long arow = (long)bm * 64 + w * 16 + ln;
    f32x4 acc[NT];
#pragma unroll
    for (int c = 0; c < NT; c++) acc[c] = (f32x4){0.f, 0.f, 0.f, 0.f};

#pragma unroll
    for (int kk = 0; kk < KS; kk++) {
        f16x8 a;
        if (AMODE == 0) {
            a = cvt8(Af32 + arow * KK + kk * 32 + 8 * lk);
        } else if (AMODE == 3) {
            a = *(const f16x8*)(Ah + arow * KK + kk * 32 + 8 * lk);
        } else {  // AMODE == 2: KK=512, halves resolve at compile time per kk
            if (kk < KS / 2)
                a = cvt8(Af32 + arow * 256 + kk * 32 + 8 * lk);
            else
                a = *(const f16x8*)(Ah + arow * 256 + (kk - KS / 2) * 32 + 8 * lk);
        }
#pragma unroll
        for (int c = 0; c < NT; c++)
            acc[c] = __builtin_amdgcn_mfma_f32_16x16x32_f16(a, bf[c][kk], acc[c], 0, 0, 0);
    }

    // ---- epilogue: C row = lk*4 + i, col = ln ----
#pragma unroll
    for (int c = 0; c < NT; c++) {
        const int n = bn * BN + c * 16 + ln;
        const float bi = (EPI == 1) ? bias[n] : 0.f;
#pragma unroll
        for (int i = 0; i < 4; i++) {
            const long m = (long)bm * 64 + w * 16 + lk * 4 + i;
            float v = acc[c][i];
            if (EPI == 1) v += bi;
            if (EPI == 2) v = fast_sigmoid(v) * (float)gateC[m * 256 + n];
            Cout[m * (long)N + n] = (_Float16)v;
        }
    }
}

// ---------------------------------------------------------------------------
// Fused attention: per block = one (p,b) pair (m = p*16+b).  (unchanged)
// ---------------------------------------------------------------------------
__global__ __launch_bounds__(256) void attn_k(
    const float* __restrict__ question,  // (Q,B,E) fp32
    const float* __restrict__ vvec,      // (H,) fp32
    const _Float16* __restrict__ Wp,     // (P*B, H) f16
    const _Float16* __restrict__ Wq,     // (Q*B, H) f16
    _Float16* __restrict__ Cc)           // (P*B, E) f16 out
{
    __shared__ float sc[QQ];
    __shared__ float aw[QQ];
    const int tid = threadIdx.x;
    const int blk = blockIdx.x;   // m = p*16 + b
    const int b = blk & 15;
    const int wave = tid >> 6, lane = tid & 63;

    float wp0[4], vv[4];
#pragma unroll
    for (int j = 0; j < 4; j++) {
        wp0[j] = (float)Wp[(long)blk * 256 + lane + 64 * j];
        vv[j] = vvec[lane + 64 * j];
    }
#pragma unroll 2
    for (int qi = 0; qi < 16; qi++) {
        const int q = wave * 16 + qi;
        const _Float16* wqp = Wq + (long)(q * 16 + b) * 256;
        float s = 0.f;
#pragma unroll
        for (int j = 0; j < 4; j++) {
            float x = (float)wqp[lane + 64 * j] + wp0[j];
            s += fast_tanh(x) * vv[j];
        }
#pragma unroll
        for (int off = 32; off; off >>= 1) s += __shfl_xor(s, off, 64);
        if (lane == 0) sc[q] = s;
    }
    __syncthreads();
    if (tid < 64) {
        float s = sc[tid];
        float mx = s;
#pragma unroll
        for (int off = 32; off; off >>= 1) mx = fmaxf(mx, __shfl_xor(mx, off, 64));
        float e = __expf(s - mx);
        float sum = e;
#pragma unroll
        for (int off = 32; off; off >>= 1) sum += __shfl_xor(sum, off, 64);
        aw[tid] = e * __frcp_rn(sum);
    }
    __syncthreads();
    float acc = 0.f;
#pragma unroll 4
    for (int q = 0; q < QQ; q++) {
        acc = fmaf(aw[q], question[(long)(q * 16 + b) * 256 + tid], acc);
    }
    Cc[(long)blk * 256 + tid] = (_Float16)acc;
}

// ---------------------------------------------------------------------------
// GRU scan, v11: HYBRID dot2+MFMA. 16 blocks (one per batch), 512 threads
// (8 waves, 2/SIMD via waves_per_eu(2,2) -> 256 unified regs).
//
// r8 conclusions: (a) dot2-only is register-structural: allocator grants
// arch ~= budget/2 (r1-r3: 128->64; r8: 256->128) and weight demand is
// always 1.5x that grant -> permanent accvgpr tax (measured 601us, VALU
// 1890 cyc/step). (b) MFMA-only floor is 384 MFMA x 16cyc/SIMD / 2 waves
// ~= 1536 cyc (M=1/16 waste; count M-independent) -> measured 622us.
// v11 splits BY GATE across the two independent pipes (m114: MFMA+VALU
// overlap, time=max not sum), using each register file for what reads it:
//   r,z gates: dot2. Thread (q,e): rows {e, e+256}, K-half q -> 128 half2
//              ARCH weights + 2-way partial exchange (v10 structure).
//   n gate:    MFMA. Wave w owns n-cols [32w,32w+32) -> bf[2][8] f16x8 =
//              64 AGPR weights; masked-A broadcast h (v6 structure,
//              hardware-verified mapping); full-K result, no combine.
// Per SIMD per step: dot2 ~512 cyc || MFMA 512 cyc, concurrent.
// Skeleton (2 LDS-only barriers, gi prefetch, 256-thread gate phase)
// unchanged from v10 (passed).
// ---------------------------------------------------------------------------
__global__ __launch_bounds__(512)
__attribute__((amdgpu_waves_per_eu(2, 2)))
void gru_k(
    const float* __restrict__ whh,    // (768,256) fp32
    const float* __restrict__ bhh,    // (768,) fp32
    const _Float16* __restrict__ gi,  // (P*B, 768) f16 (b_ih folded in)
    float* __restrict__ out)          // (P,B,O) fp32
{
    __shared__ __align__(16) _Float16 hbuf[2][256];   // h broadcast, dbuf
    __shared__ float part[2][256];                    // r,z partials (q=1)
    __shared__ float nlds[256];                       // n-gate pre-acts (MFMA)
    const int tid = threadIdx.x;
    const int q = tid >> 8;       // K-half 0/1
    const int e = tid & 255;
    const int w = tid >> 6;       // wave 0..7
    const int lane = tid & 63;
    const int b = blockIdx.x;
    const int koff = q * 128;

    // ---- dot2 weights (ARCH regs): rows e (r), e+256 (z), cols [koff,+128)
    half2_t wr[64], wz[64];
    {
        const float* pr = whh + (long)e * 256 + koff;
        const float* pz = whh + (long)(e + 256) * 256 + koff;
#pragma unroll
        for (int j = 0; j < 32; j++) {
            float4 a = *(const float4*)(pr + 4 * j);
            float4 c = *(const float4*)(pz + 4 * j);
            half2_t t;
            t[0] = (_Float16)a.x; t[1] = (_Float16)a.y; wr[2 * j] = t;
            t[0] = (_Float16)a.z; t[1] = (_Float16)a.w; wr[2 * j + 1] = t;
            t[0] = (_Float16)c.x; t[1] = (_Float16)c.y; wz[2 * j] = t;
            t[0] = (_Float16)c.z; t[1] = (_Float16)c.w; wz[2 * j + 1] = t;
        }
    }
    // ---- MFMA n-gate weights (AGPR regs): wave w owns cols [32w, 32w+32)
    // B[k][n] = whh[512 + 32w + 16c + (lane&15)][k], k = kk*32+8*(lane>>4)+j
    f16x8 bf[2][8];
#pragma unroll
    for (int c = 0; c < 2; c++) {
        const int n0 = 512 + 32 * w + 16 * c + (lane & 15);
        const float* wp = whh + (long)n0 * 256 + 8 * (lane >> 4);
#pragma unroll
        for (int kk = 0; kk < 8; kk++) bf[c][kk] = cvt8(wp + kk * 32);
    }

    float b_r = 0.f, b_z = 0.f, b_n = 0.f;
    _Float16 gr = (_Float16)0.f, gz = (_Float16)0.f, gn = (_Float16)0.f;
    const _Float16* gip = gi;
    float* outp = out;
    if (q == 0) {
        b_r = bhh[e];
        b_z = bhh[e + 256];
        b_n = bhh[e + 512];
        hbuf[0][e] = (_Float16)0.f;
        gip = gi + (long)b * 768 + e;
        gr = gip[0]; gz = gip[256]; gn = gip[512];   // step-0 gi
        outp = out + (long)b * 256 + e;
    }
    float h = 0.f;
    __syncthreads();

    // MFMA A-frag: 16-lane groups read the same 16B of h (broadcast);
    // non-row-0 lanes mask to zero (v6-verified).
    const unsigned msk = ((lane & 15) == 0) ? 0xFFFFFFFFu : 0u;

    int cur = 0;
    for (int t = 0; t < PP; t++) {
        // Prefetch NEXT step's gi (t=511 reads one row past gi -- inside
        // the 16 MiB workspace, value unused).
        _Float16 gr2 = (_Float16)0.f, gz2 = (_Float16)0.f, gn2 = (_Float16)0.f;
        if (q == 0) {
            const _Float16* gq = gip + 16 * 768;
            gr2 = gq[0]; gz2 = gq[256]; gn2 = gq[512];
        }

        // ---- n-gate MFMA (issued first: fills the MFMA pipe, dot2 VALU
        // overlaps its execution on the separate pipe) ----
        const _Float16* hbm = hbuf[cur] + 8 * (lane >> 4);
        f32x4 a20 = {0.f, 0.f, 0.f, 0.f}, a21 = {0.f, 0.f, 0.f, 0.f};
#pragma unroll
        for (int kk = 0; kk < 8; kk++) {
            uint4 ra = *(const uint4*)(hbm + kk * 32);
            ra.x &= msk; ra.y &= msk; ra.z &= msk; ra.w &= msk;
            f16x8 a = __builtin_bit_cast(f16x8, ra);
            a20 = __builtin_amdgcn_mfma_f32_16x16x32_f16(a, bf[0][kk], a20, 0, 0, 0);
            a21 = __builtin_amdgcn_mfma_f32_16x16x32_f16(a, bf[1][kk], a21, 0, 0, 0);
        }

        // ---- r,z half-dots over this thread's 128-wide k-slice ----
        const uint4* hp4 = ((const uint4*)hbuf[cur]) + q * 16;
        float ar = 0.f, az = 0.f;
#pragma unroll
        for (int j = 0; j < 16; j++) {
            uint4 hp = hp4[j];
            half2_t h0 = __builtin_bit_cast(half2_t, hp.x);
            half2_t h1 = __builtin_bit_cast(half2_t, hp.y);
            half2_t h2 = __builtin_bit_cast(half2_t, hp.z);
            half2_t h3 = __builtin_bit_cast(half2_t, hp.w);
            ar = fdot2f(wr[4 * j + 0], h0, ar);
            ar = fdot2f(wr[4 * j + 1], h1, ar);
            ar = fdot2f(wr[4 * j + 2], h2, ar);
            ar = fdot2f(wr[4 * j + 3], h3, ar);
            az = fdot2f(wz[4 * j + 0], h0, az);
            az = fdot2f(wz[4 * j + 1], h1, az);
            az = fdot2f(wz[4 * j + 2], h2, az);
            az = fdot2f(wz[4 * j + 3], h3, az);
        }

        // ---- publish: r,z partials (q=1) + n pre-acts (MFMA row 0) ----
        if (q) {
            part[0][e] = ar;
            part[1][e] = az;
        }
        if (lane < 16) {   // C row 0: col = lane&15, reg 0 (v6-verified)
            nlds[32 * w + lane] = a20[0];
            nlds[32 * w + lane + 16] = a21[0];
        }
        block_sync_lds();

        // ---- gates (threads 0-255): n arrives full-K from MFMA ----
        if (q == 0) {
            float ghr = ar + part[0][e] + b_r;
            float ghz = az + part[1][e] + b_z;
            float ghn = nlds[e] + b_n;
            float r = fast_sigmoid((float)gr + ghr);
            float z = fast_sigmoid((float)gz + ghz);
            float n = fast_tanh(fmaf(r, ghn, (float)gn));
            h = (1.f - z) * n + z * h;
            *outp = h;
            hbuf[cur ^ 1][e] = (_Float16)h;
            gr = gr2; gz = gz2; gn = gn2;
            gip += 16 * 768;
            outp += 16 * 256;
        }
        block_sync_lds();
        cur ^= 1;
    }
}

// ---------------------------------------------------------------------------
extern "C" void kernel_launch(void* const* d_in, const int* in_sizes, int n_in,
                              void* d_out, int out_size, void* d_ws, size_t ws_size,
                              hipStream_t stream)
{
    const float* passage  = (const float*)d_in[0];   // (512,16,256) fp32
    const float* question = (const float*)d_in[1];   // (64,16,256) fp32
    const float* Wuq      = (const float*)d_in[2];   // (256,256) fp32
    const float* Wup      = (const float*)d_in[3];   // (256,256) fp32
    const float* vvec     = (const float*)d_in[4];   // (1,256) fp32
    const float* Wg       = (const float*)d_in[5];   // (512,512) fp32
    const float* w_ih     = (const float*)d_in[6];   // (768,256) fp32
    const float* w_hh     = (const float*)d_in[7];   // (768,256) fp32
    const float* b_ih     = (const float*)d_in[8];   // (768,) fp32
    const float* b_hh     = (const float*)d_in[9];   // (768,) fp32

    // Workspace layout (all fp16) — total footprint exactly 16 MiB.
    //   [0,      12.0MiB) : gi (8192x768)  — written LAST; overlaps Wq/Wp/c,
    //                        which are all dead by the time gi is produced.
    //       [0,     0.5MiB) : Wq (1024x256)   dead after attn
    //       [0.5,   4.5MiB) : Wp (8192x256)   dead after attn
    //       [4.5,   8.5MiB) : c  (8192x256)   dead after gate GEMM
    //   [12MiB, 16MiB)     : cg (8192x256)    alive until gi GEMM done
    char* ws = (char*)d_ws;
    _Float16* gi_ws = (_Float16*)(ws);
    _Float16* Wq_ws = (_Float16*)(ws);
    _Float16* Wp_ws = (_Float16*)(ws + (512u << 10));
    _Float16* c_ws  = (_Float16*)(ws + (4608u << 10));
    _Float16* cg_ws = (_Float16*)(ws + (12288u << 10));

    // 1) Wq = question @ Wuq^T   (1024 x 256, K=256)
    gemm_mfma<0, 0, 64, 256><<<dim3(16, 4), 256, 0, stream>>>(
        question, nullptr, Wuq, nullptr, nullptr, Wq_ws, 1024, 256);
    // 2) Wp = passage @ Wup^T    (8192 x 256, K=256)
    gemm_mfma<0, 0, 64, 256><<<dim3(128, 4), 256, 0, stream>>>(
        passage, nullptr, Wup, nullptr, nullptr, Wp_ws, 8192, 256);
    // 3) attention -> c (8192 x 256)
    attn_k<<<8192, 256, 0, stream>>>(question, vvec, Wp_ws, Wq_ws, c_ws);
    // 4) cg = sigmoid([passage,c] @ Wg[256:512]^T) * c   (8192 x 256, K=512)
    gemm_mfma<2, 2, 32, 512><<<dim3(128, 8), 256, 0, stream>>>(
        passage, c_ws, Wg + 256 * 512, nullptr, c_ws, cg_ws, 8192, 256);
    // 5) gi = cg @ w_ih^T + b_ih   (8192 x 768, K=256)
    gemm_mfma<3, 1, 64, 256><<<dim3(128, 12), 256, 0, stream>>>(
        nullptr, cg_ws, w_ih, b_ih, nullptr, gi_ws, 8192, 768);
    // 6) GRU scan -> out (fp32)
    gru_k<<<16, 512, 0, stream>>>(w_hh, b_hh, gi_ws, (float*)d_out);
}

// Round 10
// 836.174 us; speedup vs baseline: 1.2625x; 1.2625x over previous
//
#include <hip/hip_runtime.h>
#include <hip/hip_bf16.h>

// Problem dims
#define PP 512
#define QQ 64
#define BB 16
#define EE 256
#define HH 256
#define OO 256

typedef _Float16 half2_t __attribute__((ext_vector_type(2)));
typedef _Float16 f16x8 __attribute__((ext_vector_type(8)));
typedef float f32x4 __attribute__((ext_vector_type(4)));

__device__ __forceinline__ float fast_tanh(float x) {
    x = fminf(fmaxf(x, -15.f), 15.f);
    float e = __expf(2.f * x);
    return (e - 1.f) * __frcp_rn(e + 1.f);
}
__device__ __forceinline__ float fast_sigmoid(float x) {
    x = fminf(fmaxf(x, -30.f), 30.f);
    return __frcp_rn(1.f + __expf(-x));
}
__device__ __forceinline__ f16x8 cvt8(const float* __restrict__ p) {
    float4 r0 = *(const float4*)(p);
    float4 r1 = *(const float4*)(p + 4);
    f16x8 t;
    t[0] = (_Float16)r0.x; t[1] = (_Float16)r0.y;
    t[2] = (_Float16)r0.z; t[3] = (_Float16)r0.w;
    t[4] = (_Float16)r1.x; t[5] = (_Float16)r1.y;
    t[6] = (_Float16)r1.z; t[7] = (_Float16)r1.w;
    return t;
}
__device__ __forceinline__ float fdot2f(half2_t a, half2_t b, float c) {
#if defined(__has_builtin)
#if __has_builtin(__builtin_amdgcn_fdot2)
    return __builtin_amdgcn_fdot2(a, b, c, false);
#else
    return (float)a[0] * (float)b[0] + (float)a[1] * (float)b[1] + c;
#endif
#else
    return (float)a[0] * (float)b[0] + (float)a[1] * (float)b[1] + c;
#endif
}

// LDS-only barrier: orders ds_write -> barrier -> ds_read WITHOUT the
// vmcnt(0)/expcnt(0) drain __syncthreads() emits.
__device__ __forceinline__ void block_sync_lds() {
    __builtin_amdgcn_sched_barrier(0);
    asm volatile("s_waitcnt lgkmcnt(0)" ::: "memory");
    __builtin_amdgcn_s_barrier();
    __builtin_amdgcn_sched_barrier(0);
}

// ---------------------------------------------------------------------------
// One-shot fp32->f16 pre-conversion into d_out scratch (d_out is only
// written by the FINAL gru kernel, so it's free real estate until then).
// f16-element layout in dst:
//   [0,      65536)  Wuq   (256x256)
//   [65536, 131072)  Wup   (256x256)
//   [131072,262144)  Wg2 = Wg rows [256,512)  (256x512)
//   [262144,458752)  w_ih  (768x256)
//   [458752,524288)  (gap)
//   [524288,2621440) passage (8192x256)
// Removes the per-block fp32 B-staging (64 dwordx4 loads + ~256 v_cvt per
// thread, duplicated across 4 waves x all bm blocks) from every GEMM.
// ---------------------------------------------------------------------------
__global__ __launch_bounds__(256) void conv_k(
    const float* __restrict__ Wuq, const float* __restrict__ Wup,
    const float* __restrict__ Wg2, const float* __restrict__ w_ih,
    const float* __restrict__ passage, _Float16* __restrict__ dst)
{
    const long i = ((long)blockIdx.x * 256 + threadIdx.x) * 8;
    const float* src;
    long off;
    if (i < 65536)       { src = Wuq;     off = i; }
    else if (i < 131072) { src = Wup;     off = i - 65536; }
    else if (i < 262144) { src = Wg2;     off = i - 131072; }
    else if (i < 458752) { src = w_ih;    off = i - 262144; }
    else if (i < 524288) { return; }
    else                 { src = passage; off = i - 524288; }
    *(f16x8*)(dst + i) = cvt8(src + off);
}

// ---------------------------------------------------------------------------
// MFMA GEMM, register-resident f16 B (pre-converted by conv_k).
// Per thread: 32 direct 16B f16 loads stage the whole B-strip; no cvt.
// AMODE: 0 = A fp32 (row stride KK)          [question]
//        3 = A f16 via Ah (row stride KK)    [passage_h / cg]
//        2 = concat: k<256 -> Ah2 f16 (stride 256), k>=256 -> Ah f16
// EPI:   0 none | 1 +bias[n] | 2 sigmoid(acc)*gateC[m*256+n]
// Fragment mappings hardware-verified by the v6 GRU kernel.
// ---------------------------------------------------------------------------
template <int AMODE, int EPI, int BN, int KK>
__global__ __launch_bounds__(256)
__attribute__((amdgpu_waves_per_eu(2, 2)))
void gemm_mfma(
    const float* __restrict__ Af32,
    const _Float16* __restrict__ Ah,
    const _Float16* __restrict__ Ah2,
    const _Float16* __restrict__ Bh,
    const float* __restrict__ bias,
    const _Float16* __restrict__ gateC,
    _Float16* __restrict__ Cout, int M, int N)
{
    constexpr int NT = BN / 16;   // n-tiles per block (4 or 2)
    constexpr int KS = KK / 32;   // k-steps (8 or 16)
    const int tid = threadIdx.x;
    const int w = tid >> 6;
    const int lane = tid & 63;
    const int ln = lane & 15;     // fragment n / m index
    const int lk = lane >> 4;     // fragment k-group
    const int bm = blockIdx.x, bn = blockIdx.y;

    // ---- park B-strip in fragments (AGPR-resident across the k-loop) ----
    f16x8 bf[NT][KS];
#pragma unroll
    for (int c = 0; c < NT; c++) {
        const _Float16* wp = Bh + (long)(bn * BN + c * 16 + ln) * KK + 8 * lk;
#pragma unroll
        for (int kk = 0; kk < KS; kk++)
            bf[c][kk] = *(const f16x8*)(wp + kk * 32);
    }

    const long arow = (long)bm * 64 + w * 16 + ln;
    f32x4 acc[NT];
#pragma unroll
    for (int c = 0; c < NT; c++) acc[c] = (f32x4){0.f, 0.f, 0.f, 0.f};

#pragma unroll
    for (int kk = 0; kk < KS; kk++) {
        f16x8 a;
        if (AMODE == 0) {
            a = cvt8(Af32 + arow * KK + kk * 32 + 8 * lk);
        } else if (AMODE == 3) {
            a = *(const f16x8*)(Ah + arow * KK + kk * 32 + 8 * lk);
        } else {  // AMODE == 2: KK=512, halves resolve at compile time per kk
            if (kk < KS / 2)
                a = *(const f16x8*)(Ah2 + arow * 256 + kk * 32 + 8 * lk);
            else
                a = *(const f16x8*)(Ah + arow * 256 + (kk - KS / 2) * 32 + 8 * lk);
        }
#pragma unroll
        for (int c = 0; c < NT; c++)
            acc[c] = __builtin_amdgcn_mfma_f32_16x16x32_f16(a, bf[c][kk], acc[c], 0, 0, 0);
    }

    // ---- epilogue: C row = lk*4 + i, col = ln ----
#pragma unroll
    for (int c = 0; c < NT; c++) {
        const int n = bn * BN + c * 16 + ln;
        const float bi = (EPI == 1) ? bias[n] : 0.f;
#pragma unroll
        for (int i = 0; i < 4; i++) {
            const long m = (long)bm * 64 + w * 16 + lk * 4 + i;
            float v = acc[c][i];
            if (EPI == 1) v += bi;
            if (EPI == 2) v = fast_sigmoid(v) * (float)gateC[m * 256 + n];
            Cout[m * (long)N + n] = (_Float16)v;
        }
    }
}

// ---------------------------------------------------------------------------
// Fused attention: per block = one (p,b) pair (m = p*16+b).  (unchanged)
// ---------------------------------------------------------------------------
__global__ __launch_bounds__(256) void attn_k(
    const float* __restrict__ question,  // (Q,B,E) fp32
    const float* __restrict__ vvec,      // (H,) fp32
    const _Float16* __restrict__ Wp,     // (P*B, H) f16
    const _Float16* __restrict__ Wq,     // (Q*B, H) f16
    _Float16* __restrict__ Cc)           // (P*B, E) f16 out
{
    __shared__ float sc[QQ];
    __shared__ float aw[QQ];
    const int tid = threadIdx.x;
    const int blk = blockIdx.x;   // m = p*16 + b
    const int b = blk & 15;
    const int wave = tid >> 6, lane = tid & 63;

    float wp0[4], vv[4];
#pragma unroll
    for (int j = 0; j < 4; j++) {
        wp0[j] = (float)Wp[(long)blk * 256 + lane + 64 * j];
        vv[j] = vvec[lane + 64 * j];
    }
#pragma unroll 2
    for (int qi = 0; qi < 16; qi++) {
        const int q = wave * 16 + qi;
        const _Float16* wqp = Wq + (long)(q * 16 + b) * 256;
        float s = 0.f;
#pragma unroll
        for (int j = 0; j < 4; j++) {
            float x = (float)wqp[lane + 64 * j] + wp0[j];
            s += fast_tanh(x) * vv[j];
        }
#pragma unroll
        for (int off = 32; off; off >>= 1) s += __shfl_xor(s, off, 64);
        if (lane == 0) sc[q] = s;
    }
    __syncthreads();
    if (tid < 64) {
        float s = sc[tid];
        float mx = s;
#pragma unroll
        for (int off = 32; off; off >>= 1) mx = fmaxf(mx, __shfl_xor(mx, off, 64));
        float e = __expf(s - mx);
        float sum = e;
#pragma unroll
        for (int off = 32; off; off >>= 1) sum += __shfl_xor(sum, off, 64);
        aw[tid] = e * __frcp_rn(sum);
    }
    __syncthreads();
    float acc = 0.f;
#pragma unroll 4
    for (int q = 0; q < QQ; q++) {
        acc = fmaf(aw[q], question[(long)(q * 16 + b) * 256 + tid], acc);
    }
    Cc[(long)blk * 256 + tid] = (_Float16)acc;
}

// ---------------------------------------------------------------------------
// GRU scan, v10 (RESTORED -- best measured: 601us). 16 blocks, 512 threads
// (8 waves, 2/SIMD via waves_per_eu(2,2) -> 256 unified regs).
// r9 post-mortem closed the hybrid path: same-wave MFMA+dot2 serializes
// (barrier-locked waves hit the MFMA phase together; m114 overlap needs
// role-split waves), and the accvgpr tax persists (arch ~= budget/2).
// Both pure engines measured at their floors (dot2 601, MFMA 622);
// this is the scan's practical plateau.
// ---------------------------------------------------------------------------
__global__ __launch_bounds__(512)
__attribute__((amdgpu_waves_per_eu(2, 2), amdgpu_num_vgpr(256)))
void gru_k(
    const float* __restrict__ whh,    // (768,256) fp32
    const float* __restrict__ bhh,    // (768,) fp32
    const _Float16* __restrict__ gi,  // (P*B, 768) f16 (b_ih folded in)
    float* __restrict__ out)          // (P,B,O) fp32
{
    __shared__ __align__(16) _Float16 hbuf[2][256];   // h broadcast, dbuf
    __shared__ float part[3][256];                    // q=1 partials
    const int tid = threadIdx.x;
    const int q = tid >> 8;       // K-half 0/1
    const int e = tid & 255;
    const int b = blockIdx.x;
    const int koff = q * 128;

    // Weight slices: rows e (r), e+256 (z), e+512 (n), cols [koff, koff+128)
    half2_t wr[64], wz[64], wn[64];
    {
        const float* pr = whh + (long)e * 256 + koff;
        const float* pz = whh + (long)(e + 256) * 256 + koff;
        const float* pn = whh + (long)(e + 512) * 256 + koff;
#pragma unroll
        for (int j = 0; j < 32; j++) {
            float4 a = *(const float4*)(pr + 4 * j);
            float4 c = *(const float4*)(pz + 4 * j);
            float4 d = *(const float4*)(pn + 4 * j);
            half2_t t;
            t[0] = (_Float16)a.x; t[1] = (_Float16)a.y; wr[2 * j] = t;
            t[0] = (_Float16)a.z; t[1] = (_Float16)a.w; wr[2 * j + 1] = t;
            t[0] = (_Float16)c.x; t[1] = (_Float16)c.y; wz[2 * j] = t;
            t[0] = (_Float16)c.z; t[1] = (_Float16)c.w; wz[2 * j + 1] = t;
            t[0] = (_Float16)d.x; t[1] = (_Float16)d.y; wn[2 * j] = t;
            t[0] = (_Float16)d.z; t[1] = (_Float16)d.w; wn[2 * j + 1] = t;
        }
    }
    float b_r = 0.f, b_z = 0.f, b_n = 0.f;
    _Float16 gr = (_Float16)0.f, gz = (_Float16)0.f, gn = (_Float16)0.f;
    const _Float16* gip = gi;
    float* outp = out;
    if (q == 0) {
        b_r = bhh[e];
        b_z = bhh[e + 256];
        b_n = bhh[e + 512];
        hbuf[0][e] = (_Float16)0.f;
        gip = gi + (long)b * 768 + e;
        gr = gip[0]; gz = gip[256]; gn = gip[512];   // step-0 gi
        outp = out + (long)b * 256 + e;
    }
    float h = 0.f;
    __syncthreads();

    int cur = 0;
    for (int t = 0; t < PP; t++) {
        // Prefetch NEXT step's gi. t=511 reads one row past gi -- inside
        // the 16 MiB workspace, value unused.
        _Float16 gr2 = (_Float16)0.f, gz2 = (_Float16)0.f, gn2 = (_Float16)0.f;
        if (q == 0) {
            const _Float16* gq = gip + 16 * 768;
            gr2 = gq[0]; gz2 = gq[256]; gn2 = gq[512];
        }
        // Half-dot over this thread's 128-wide k-slice of the broadcast h.
        const uint4* hp4 = ((const uint4*)hbuf[cur]) + q * 16;
        float ar = 0.f, az = 0.f, an = 0.f;
#pragma unroll
        for (int j = 0; j < 16; j++) {
            uint4 hp = hp4[j];
            half2_t h0 = __builtin_bit_cast(half2_t, hp.x);
            half2_t h1 = __builtin_bit_cast(half2_t, hp.y);
            half2_t h2 = __builtin_bit_cast(half2_t, hp.z);
            half2_t h3 = __builtin_bit_cast(half2_t, hp.w);
            ar = fdot2f(wr[4 * j + 0], h0, ar);
            ar = fdot2f(wr[4 * j + 1], h1, ar);
            ar = fdot2f(wr[4 * j + 2], h2, ar);
            ar = fdot2f(wr[4 * j + 3], h3, ar);
            az = fdot2f(wz[4 * j + 0], h0, az);
            az = fdot2f(wz[4 * j + 1], h1, az);
            az = fdot2f(wz[4 * j + 2], h2, az);
            az = fdot2f(wz[4 * j + 3], h3, az);
            an = fdot2f(wn[4 * j + 0], h0, an);
            an = fdot2f(wn[4 * j + 1], h1, an);
            an = fdot2f(wn[4 * j + 2], h2, an);
            an = fdot2f(wn[4 * j + 3], h3, an);
        }
        if (q) {
            part[0][e] = ar;
            part[1][e] = az;
            part[2][e] = an;
        }
        block_sync_lds();
        if (q == 0) {
            float ghr = ar + part[0][e] + b_r;
            float ghz = az + part[1][e] + b_z;
            float ghn = an + part[2][e] + b_n;
            float r = fast_sigmoid((float)gr + ghr);
            float z = fast_sigmoid((float)gz + ghz);
            float n = fast_tanh(fmaf(r, ghn, (float)gn));
            h = (1.f - z) * n + z * h;
            *outp = h;
            hbuf[cur ^ 1][e] = (_Float16)h;
            gr = gr2; gz = gz2; gn = gn2;
            gip += 16 * 768;
            outp += 16 * 256;
        }
        block_sync_lds();
        cur ^= 1;
    }
}

// ---------------------------------------------------------------------------
extern "C" void kernel_launch(void* const* d_in, const int* in_sizes, int n_in,
                              void* d_out, int out_size, void* d_ws, size_t ws_size,
                              hipStream_t stream)
{
    const float* passage  = (const float*)d_in[0];   // (512,16,256) fp32
    const float* question = (const float*)d_in[1];   // (64,16,256) fp32
    const float* Wuq      = (const float*)d_in[2];   // (256,256) fp32
    const float* Wup      = (const float*)d_in[3];   // (256,256) fp32
    const float* vvec     = (const float*)d_in[4];   // (1,256) fp32
    const float* Wg       = (const float*)d_in[5];   // (512,512) fp32
    const float* w_ih     = (const float*)d_in[6];   // (768,256) fp32
    const float* w_hh     = (const float*)d_in[7];   // (768,256) fp32
    const float* b_ih     = (const float*)d_in[8];   // (768,) fp32
    const float* b_hh     = (const float*)d_in[9];   // (768,) fp32

    // Workspace layout (all fp16) — total footprint exactly 16 MiB.
    //   [0,      12.0MiB) : gi (8192x768)  — written LAST; overlaps Wq/Wp/c.
    //       [0,     0.5MiB) : Wq (1024x256)   dead after attn
    //       [0.5,   4.5MiB) : Wp (8192x256)   dead after attn
    //       [4.5,   8.5MiB) : c  (8192x256)   dead after gate GEMM
    //   [12MiB, 16MiB)     : cg (8192x256)    alive until gi GEMM done
    // d_out (8 MiB fp32 out) doubles as f16 scratch for pre-converted
    // weights + passage until gru_k (the only writer of out) runs.
    char* ws = (char*)d_ws;
    _Float16* gi_ws = (_Float16*)(ws);
    _Float16* Wq_ws = (_Float16*)(ws);
    _Float16* Wp_ws = (_Float16*)(ws + (512u << 10));
    _Float16* c_ws  = (_Float16*)(ws + (4608u << 10));
    _Float16* cg_ws = (_Float16*)(ws + (12288u << 10));

    _Float16* wh     = (_Float16*)d_out;      // f16 scratch
    _Float16* wuq_h  = wh;                    // 256x256
    _Float16* wup_h  = wh + 65536;            // 256x256
    _Float16* wg2_h  = wh + 131072;           // 256x512
    _Float16* wih_h  = wh + 262144;           // 768x256
    _Float16* pass_h = wh + 524288;           // 8192x256

    // 0) one-shot fp32->f16 conversion (weights + passage) into d_out
    conv_k<<<1280, 256, 0, stream>>>(Wuq, Wup, Wg + 256 * 512, w_ih, passage, wh);
    // 1) Wq = question @ Wuq^T   (1024 x 256, K=256)
    gemm_mfma<0, 0, 64, 256><<<dim3(16, 4), 256, 0, stream>>>(
        question, nullptr, nullptr, wuq_h, nullptr, nullptr, Wq_ws, 1024, 256);
    // 2) Wp = passage @ Wup^T    (8192 x 256, K=256)
    gemm_mfma<3, 0, 64, 256><<<dim3(128, 4), 256, 0, stream>>>(
        nullptr, pass_h, nullptr, wup_h, nullptr, nullptr, Wp_ws, 8192, 256);
    // 3) attention -> c (8192 x 256)
    attn_k<<<8192, 256, 0, stream>>>(question, vvec, Wp_ws, Wq_ws, c_ws);
    // 4) cg = sigmoid([passage,c] @ Wg[256:512]^T) * c   (8192 x 256, K=512)
    gemm_mfma<2, 2, 32, 512><<<dim3(128, 8), 256, 0, stream>>>(
        nullptr, c_ws, pass_h, wg2_h, nullptr, c_ws, cg_ws, 8192, 256);
    // 5) gi = cg @ w_ih^T + b_ih   (8192 x 768, K=256)
    gemm_mfma<3, 1, 64, 256><<<dim3(128, 12), 256, 0, stream>>>(
        nullptr, cg_ws, nullptr, wih_h, b_ih, nullptr, gi_ws, 8192, 768);
    // 6) GRU scan -> out (fp32; overwrites the scratch)
    gru_k<<<16, 512, 0, stream>>>(w_hh, b_hh, gi_ws, (float*)d_out);
}